// Round 5
// baseline (157.882 us; speedup 1.0000x reference)
//
#include <hip/hip_runtime.h>
#include <math.h>

typedef unsigned int uint;
typedef unsigned short ushort;
typedef short s16x8 __attribute__((ext_vector_type(8)));
typedef float f32x4 __attribute__((ext_vector_type(4)));
typedef uint u32x4 __attribute__((ext_vector_type(4)));

#define L     880
#define LP    896
#define NC    64
#define WS    (NC * LP)      // elements per W slab
#define DS    48
#define OUTD  96
#define KCV   3072           // padded conv K (63*48=3024 real)
#define NZ    3

// ws layout (float offsets). E planes bf16 LP*LP = 401408 floats each.
// order: EN1,ET1,EN2,ET2,EN4,ET4,EN8,ET8,EN16,ET16,EN32
#define OFF_E    0
#define OFF_WF   4415488                    // 64 slabs f32 (incl. W63 pad)
#define OFF_WB   (OFF_WF + 64 * WS)         // 64 slabs bf16
#define OFF_KDT  (OFF_WB + 64 * WS / 2)     // 896x3072 bf16
#define OFF_U    (OFF_KDT + LP * KCV / 2)   // 256x3072 bf16
#define OFF_PART (OFF_U + 256 * KCV / 2)    // NZ x 256 x 896 f32
// total = OFF_PART + NZ*256*LP = 12378112 floats = 49.5 MiB

__device__ inline ushort f2b(float f) {
  uint u = __builtin_bit_cast(uint, f);
  u += 0x7fffu + ((u >> 16) & 1u);
  return (ushort)(u >> 16);
}
__device__ inline float b2f(ushort b) {
  uint u = ((uint)b) << 16;
  return __builtin_bit_cast(float, u);
}

// ================= fused prep: E1(N+T) | W0 | U =================
__global__ __launch_bounds__(256) void k_prep(const float* __restrict__ A,
                                              const float* __restrict__ B,
                                              const float* __restrict__ th0,
                                              const float* __restrict__ xs,
                                              ushort* __restrict__ EN,
                                              ushort* __restrict__ ET,
                                              float* __restrict__ WF,
                                              ushort* __restrict__ WB,
                                              ushort* __restrict__ U) {
  const int blk = blockIdx.x;
  const int tid = threadIdx.x;
  if (blk < 196) {                       // ---- E1 = A - 0.99I, 64x64 tile ----
    __shared__ float T[64][65];
    const int bi = (blk / 14) * 64, bj = (blk % 14) * 64;
    const int r = tid >> 2, c0 = (tid & 3) * 16;
    const int gi = bi + r;
#pragma unroll
    for (int q = 0; q < 4; ++q) {
      int c = c0 + q * 4, gj = bj + c;
      float4 v = {0.f, 0.f, 0.f, 0.f};
      if (gi < L && gj + 3 < L) {
        v = *(const float4*)(A + (size_t)gi * L + gj);
      } else if (gi < L) {
        if (gj + 0 < L) v.x = A[(size_t)gi * L + gj];
        if (gj + 1 < L) v.y = A[(size_t)gi * L + gj + 1];
        if (gj + 2 < L) v.z = A[(size_t)gi * L + gj + 2];
        if (gj + 3 < L) v.w = A[(size_t)gi * L + gj + 3];
      }
      if (gi == gj)     v.x -= 0.99f;
      if (gi == gj + 1) v.y -= 0.99f;
      if (gi == gj + 2) v.z -= 0.99f;
      if (gi == gj + 3) v.w -= 0.99f;
      T[r][c] = v.x; T[r][c + 1] = v.y; T[r][c + 2] = v.z; T[r][c + 3] = v.w;
    }
    __syncthreads();
    {
      union { ushort s[16]; u32x4 v[2]; } pk;
#pragma unroll
      for (int i = 0; i < 16; ++i) pk.s[i] = f2b(T[r][c0 + i]);
      *(u32x4*)(EN + (size_t)(bi + r) * LP + bj + c0)     = pk.v[0];
      *(u32x4*)(EN + (size_t)(bi + r) * LP + bj + c0 + 8) = pk.v[1];
    }
    {
      union { ushort s[16]; u32x4 v[2]; } pk;
#pragma unroll
      for (int i = 0; i < 16; ++i) pk.s[i] = f2b(T[c0 + i][r]);
      *(u32x4*)(ET + (size_t)(bj + r) * LP + bi + c0)     = pk.v[0];
      *(u32x4*)(ET + (size_t)(bj + r) * LP + bi + c0 + 8) = pk.v[1];
    }
  } else if (blk < 420) {                // ---- W0 slab ----
    int idx = (blk - 196) * 256 + tid;   // NC*LP
    int c = idx / LP, l = idx % LP;
    float v = 0.f;
    if (l < L) {
      if (c < DS) v = B[l * DS + c];
      else if (c == DS) v = th0[l];
      else if (c < 53) {
        int b = c - 49;
        float s = 0.f;
        for (int d = 0; d < DS; ++d) s += B[l * DS + d] * xs[(b * 64) * DS + d];
        v = -s;
      }
    }
    WF[idx] = v;
    WB[idx] = f2b(v);
  } else {                               // ---- U gather (bf16, 4/thread) ----
    int idx = ((blk - 420) * 256 + tid) * 4;   // 256*KCV
    int rr = idx / KCV, k = idx - rr * KCV;
    ushort4 v = {0, 0, 0, 0};
    if (rr < 252 && k < 3024) {
      int b = rr / 63, tau = rr - b * 63;
      int j = k / DS, d = k - j * DS;
      int s = tau - j; if (s < 0) s += 63;
      float4 x4 = *(const float4*)(xs + (size_t)(b * 64 + s + 1) * DS + d);
      v.x = f2b(x4.x); v.y = f2b(x4.y); v.z = f2b(x4.z); v.w = f2b(x4.w);
    }
    *(ushort4*)(U + idx) = v;
  }
}

// ================= GEMM core geometry =================
// C[m][n] = sum_k Aop[m][k] * BopT[n][k]. Tile BM=128, BN=64, BK=64.
// 4 waves, each 64x32 out via 4x2 frags of mfma_f32_16x16x32_bf16.
#define LAD_ITERS (LP / 64)

#define GEMM_CORE(Aop, BopT, Kdim, kIters, kOff, Mv, m0, n0)                       \
  const int ar = tid >> 3;                                                         \
  const int ak = (tid & 7) * 8;                                                    \
  const int br = tid >> 2;                                                         \
  const int bk = (tid & 3) * 8;                                                    \
  const ushort* ap[4];                                                             \
  _Pragma("unroll")                                                                \
  for (int i = 0; i < 4; ++i) {                                                    \
    int rowi = m0 + ar + i * 32;                                                   \
    if (rowi > Mv - 1) rowi = Mv - 1;                                              \
    ap[i] = Aop + (size_t)rowi * Kdim + kOff + ak;                                 \
  }                                                                                \
  const ushort* bp0 = BopT + (size_t)(n0 + br) * Kdim + kOff + bk;                 \
  const ushort* bp1 = bp0 + 32;                                                    \
  const int wv = tid >> 6, lane = tid & 63;                                        \
  const int wm = (wv >> 1) * 64, wn = (wv & 1) * 32;                               \
  const int lr = lane & 15, lg = lane >> 4;                                        \
  f32x4 acc[4][2] = {};                                                            \
  u32x4 ra[4], rb[2];                                                              \
  _Pragma("unroll")                                                                \
  for (int i = 0; i < 4; ++i) ra[i] = *(const u32x4*)ap[i];                        \
  rb[0] = *(const u32x4*)bp0;                                                      \
  rb[1] = *(const u32x4*)bp1;                                                      \
  for (int it = 0; it < kIters; ++it) {                                            \
    const int cur = it & 1;                                                        \
    _Pragma("unroll")                                                              \
    for (int i = 0; i < 4; ++i) *(u32x4*)&As[cur][ar + i * 32][ak] = ra[i];        \
    *(u32x4*)&Bs[cur][br][bk]      = rb[0];                                        \
    *(u32x4*)&Bs[cur][br][bk + 32] = rb[1];                                        \
    __syncthreads();                                                               \
    if (it + 1 < kIters) {                                                         \
      _Pragma("unroll")                                                            \
      for (int i = 0; i < 4; ++i) ra[i] = *(const u32x4*)(ap[i] + (it + 1) * 64);  \
      rb[0] = *(const u32x4*)(bp0 + (it + 1) * 64);                                \
      rb[1] = *(const u32x4*)(bp1 + (it + 1) * 64);                                \
    }                                                                              \
    _Pragma("unroll")                                                              \
    for (int k2 = 0; k2 < 2; ++k2) {                                               \
      s16x8 af[4], bf[2];                                                          \
      _Pragma("unroll")                                                            \
      for (int m = 0; m < 4; ++m) af[m] = *(const s16x8*)&As[cur][wm + m * 16 + lr][k2 * 32 + lg * 8]; \
      _Pragma("unroll")                                                            \
      for (int n = 0; n < 2; ++n) bf[n] = *(const s16x8*)&Bs[cur][wn + n * 16 + lr][k2 * 32 + lg * 8]; \
      _Pragma("unroll")                                                            \
      for (int m = 0; m < 4; ++m)                                                  \
        _Pragma("unroll")                                                          \
        for (int n = 0; n < 2; ++n)                                                \
          acc[m][n] = __builtin_amdgcn_mfma_f32_16x16x32_bf16(af[m], bf[n], acc[m][n], 0, 0, 0); \
    }                                                                              \
  }

// ================= ladder: [sq E_t -> E_2t | chain W] =================
__global__ __launch_bounds__(256) void k_ladder(
    const ushort* __restrict__ sqA, const ushort* __restrict__ sqBT, float cs2,
    ushort* __restrict__ sqOutN, ushort* __restrict__ sqOutT, int ySq,
    const ushort* __restrict__ chA, const ushort* __restrict__ chBT, float csc,
    const float* __restrict__ chWFin, float* __restrict__ chWFout,
    ushort* __restrict__ chWBout, int Mv) {
  __shared__ __align__(16) ushort As[2][128][72];
  __shared__ __align__(16) ushort Bs[2][64][72];
  const int tid = threadIdx.x;
  const bool isSq = (int)blockIdx.y < ySq;
  const int n0 = blockIdx.x * 64;
  const int m0 = isSq ? blockIdx.y * 128 : ((int)blockIdx.y - ySq) * 128;
  const int MvEff = isSq ? LP : Mv;
  const ushort* Ab = isSq ? sqA : chA;
  const ushort* Bb = isSq ? sqBT : chBT;
  GEMM_CORE(Ab, Bb, LP, LAD_ITERS, 0, MvEff, m0, n0)
  if (isSq) {
    // E_2t = E_t^2 + cs2*E_t ; natural out + optional transposed via LDS bounce
    ushort* T = &As[0][0][0];                 // view [64][136]
#pragma unroll
    for (int fm = 0; fm < 4; ++fm)
#pragma unroll
      for (int fn = 0; fn < 2; ++fn)
#pragma unroll
        for (int rr = 0; rr < 4; ++rr) {
          int mi = wm + fm * 16 + lg * 4 + rr;
          int ni = wn + fn * 16 + lr;
          float v = acc[fm][fn][rr] + cs2 * b2f(sqA[(size_t)(m0 + mi) * LP + n0 + ni]);
          ushort bv = f2b(v);
          sqOutN[(size_t)(m0 + mi) * LP + n0 + ni] = bv;
          T[ni * 136 + mi] = bv;
        }
    if (sqOutT) {
      __syncthreads();
      const int nr = tid >> 2, seg = (tid & 3) * 32;
#pragma unroll
      for (int q = 0; q < 4; ++q) {
        u32x4 o = *(const u32x4*)&T[nr * 136 + seg + q * 8];
        *(u32x4*)(sqOutT + (size_t)(n0 + nr) * LP + m0 + seg + q * 8) = o;
      }
    }
  } else {
    // W_{t+s} = c_s * W_t + W_t . E_s
#pragma unroll
    for (int fm = 0; fm < 4; ++fm)
#pragma unroll
      for (int fn = 0; fn < 2; ++fn)
#pragma unroll
        for (int rr = 0; rr < 4; ++rr) {
          int mi = wm + fm * 16 + lg * 4 + rr;
          int m = m0 + mi;
          if (m < Mv) {
            int n = n0 + wn + fn * 16 + lr;
            float v = acc[fm][fn][rr] + csc * chWFin[(size_t)m * LP + n];
            chWFout[(size_t)m * LP + n] = v;
            chWBout[(size_t)m * LP + n] = f2b(v);
          }
        }
  }
}

// ================= conv GEMM: part[z][r][l] = sum_k U[r][k]*KDT[l][k] =================
__global__ __launch_bounds__(256) void k_conv(const ushort* __restrict__ U,
                                              const ushort* __restrict__ KDT,
                                              float* __restrict__ part) {
  __shared__ __align__(16) ushort As[2][128][72];
  __shared__ __align__(16) ushort Bs[2][64][72];
  const int tid = threadIdx.x;
  const int n0 = blockIdx.x * 64;
  const int m0 = blockIdx.y * 128;
  const int kOff = blockIdx.z * (KCV / NZ);
  GEMM_CORE(U, KDT, KCV, (KCV / NZ) / 64, kOff, 256, m0, n0)
  float* pp = part + (size_t)blockIdx.z * (256 * LP);
#pragma unroll
  for (int fm = 0; fm < 4; ++fm)
#pragma unroll
    for (int fn = 0; fn < 2; ++fn)
#pragma unroll
      for (int rr = 0; rr < 4; ++rr) {
        int m = m0 + wm + fm * 16 + lg * 4 + rr;
        int n = n0 + wn + fn * 16 + lr;
        pp[(size_t)m * LP + n] = acc[fm][fn][rr];
      }
}

// ================= KDT[l][j*48+d] = W_j[d][l] - W_{j-1}[d][l] =================
__global__ void k_kd(const float* __restrict__ WF, ushort* __restrict__ KDT) {
  __shared__ float D[48][65];
  const int j = blockIdx.y;          // 0..63 (63 -> zero pad)
  const int l0 = blockIdx.x * 64;
  if (j < 63) {
    const float* Wj = WF + (size_t)j * WS;
    for (int e = threadIdx.x; e < 48 * 64; e += 256) {
      int d = e >> 6, ll = e & 63;
      float v = Wj[d * LP + l0 + ll];
      if (j > 0) v -= Wj[-(int)WS + d * LP + l0 + ll];
      D[d][ll] = v;
    }
  } else {
    for (int e = threadIdx.x; e < 48 * 64; e += 256) { int d = e >> 6, ll = e & 63; D[d][ll] = 0.f; }
  }
  __syncthreads();
  for (int e = threadIdx.x; e < 48 * 64; e += 256) {
    int ll = e / 48, d = e - ll * 48;
    KDT[(size_t)(l0 + ll) * KCV + j * 48 + d] = f2b(D[d][ll]);
  }
}

// ================= final: assemble theta row in LDS, decode =================
__global__ __launch_bounds__(256) void k_final(const float* __restrict__ part,
                                               const float* __restrict__ WF,
                                               const float* __restrict__ th0,
                                               const float* __restrict__ ts,
                                               float* __restrict__ out) {
  __shared__ float th[LP];
  const int bt = blockIdx.x, b = bt >> 6, t = bt & 63;
  for (int l = threadIdx.x; l < LP; l += 256) {
    float v = 0.f;
    if (l < L) {
      if (t == 0) v = th0[l];
      else {
        int rr = b * 63 + (t - 1);
        v = part[(size_t)rr * LP + l]
          + part[(size_t)(256 * LP) + rr * LP + l]
          + part[(size_t)(2 * 256 * LP) + rr * LP + l];
        int tau = t - 1;
        v += WF[(size_t)tau * WS + DS * LP + l];
        int tw = (tau + 62) % 63;
        v += WF[(size_t)tw * WS + (49 + b) * LP + l];
      }
    }
    th[l] = v;
  }
  __syncthreads();
  int o = threadIdx.x;
  if (o < OUTD) {
    float tv = ts[bt];
    float acc = th[784 + o];
#pragma unroll
    for (int i = 0; i < 8; ++i) {
      float h = fmaxf(th[i] * tv + th[8 + i], 0.f);
      acc += th[16 + o * 8 + i] * h;
    }
    float rs;
    if (o < DS) rs = tanhf(acc);
    else        rs = fmaxf(acc, 0.f) + log1pf(expf(-fabsf(acc)));
    out[bt * OUTD + o] = rs;
  }
}

extern "C" void kernel_launch(void* const* d_in, const int* in_sizes, int n_in,
                              void* d_out, int out_size, void* d_ws, size_t ws_size,
                              hipStream_t stream) {
  const float* xs  = (const float*)d_in[0];
  const float* ts  = (const float*)d_in[1];
  const float* th0 = (const float*)d_in[2];
  const float* A   = (const float*)d_in[3];
  const float* B   = (const float*)d_in[4];
  float* out = (float*)d_out;
  float* ws  = (float*)d_ws;

  ushort* EP   = (ushort*)(ws + OFF_E);
  const size_t PL = (size_t)LP * LP;
  ushort* EN1  = EP + 0 * PL;
  ushort* ET1  = EP + 1 * PL;
  ushort* EN2  = EP + 2 * PL;
  ushort* ET2  = EP + 3 * PL;
  ushort* EN4  = EP + 4 * PL;
  ushort* ET4  = EP + 5 * PL;
  ushort* EN8  = EP + 6 * PL;
  ushort* ET8  = EP + 7 * PL;
  ushort* EN16 = EP + 8 * PL;
  ushort* ET16 = EP + 9 * PL;
  ushort* EN32 = EP + 10 * PL;
  float*  WF   = ws + OFF_WF;
  ushort* WB   = (ushort*)(ws + OFF_WB);
  ushort* KDT  = (ushort*)(ws + OFF_KDT);
  ushort* U    = (ushort*)(ws + OFF_U);
  float*  part = ws + OFF_PART;

  const float c1 = 0.99f;
  const float c2 = c1 * c1, c4 = c2 * c2, c8 = c4 * c4, c16 = c8 * c8, c32 = c16 * c16;

  k_prep<<<1188, 256, 0, stream>>>(A, B, th0, xs, EN1, ET1, WF, WB, U);

  // L1: sq E1->E2(+T) || W1 = c1*W0 + W0.E1   (chain M=64, guarded)
  k_ladder<<<dim3(14, 8), 256, 0, stream>>>(EN1, ET1, 2.f * c1, EN2, ET2, 7,
                                            WB, EN1, c1, WF, WF + 1 * WS, WB + (size_t)1 * WS, 64);
  // L2: sq E2->E4(+T) || W2,3
  k_ladder<<<dim3(14, 8), 256, 0, stream>>>(EN2, ET2, 2.f * c2, EN4, ET4, 7,
                                            WB, EN2, c2, WF, WF + 2 * WS, WB + (size_t)2 * WS, 128);
  // L3: sq E4->E8(+T) || W4..7
  k_ladder<<<dim3(14, 9), 256, 0, stream>>>(EN4, ET4, 2.f * c4, EN8, ET8, 7,
                                            WB, EN4, c4, WF, WF + 4 * WS, WB + (size_t)4 * WS, 256);
  // L4: sq E8->E16(+T) || W8..15
  k_ladder<<<dim3(14, 11), 256, 0, stream>>>(EN8, ET8, 2.f * c8, EN16, ET16, 7,
                                             WB, EN8, c8, WF, WF + 8 * WS, WB + (size_t)8 * WS, 512);
  // L5: sq E16->E32 (no T) || W16..31
  k_ladder<<<dim3(14, 15), 256, 0, stream>>>(EN16, ET16, 2.f * c16, EN32, nullptr, 7,
                                             WB, EN16, c16, WF, WF + 16 * WS, WB + (size_t)16 * WS, 1024);
  // L6: chain-only W32..63 (W63 = pad, harmless)
  k_ladder<<<dim3(14, 16), 256, 0, stream>>>(nullptr, nullptr, 0.f, nullptr, nullptr, 0,
                                             WB, EN32, c32, WF, WF + 32 * WS, WB + (size_t)32 * WS, 2048);

  k_kd<<<dim3(14, 64), 256, 0, stream>>>(WF, KDT);
  k_conv<<<dim3(14, 2, NZ), 256, 0, stream>>>(U, KDT, part);
  k_final<<<256, 256, 0, stream>>>(part, WF, th0, ts, out);
}